// Round 1
// baseline (568.115 us; speedup 1.0000x reference)
//
#include <hip/hip_runtime.h>
#include <math.h>

// Problem constants
// B=64, N=384, NFEAT=16, E=3, NHID=NOUT=128, ST_HID=64, ST_OUT=16
#define ROWS 24576            // B*N
#define ADJ_BE (384*384)      // per (b,e) adj matrix elems

// ---------------- kernel 1: h0 = x @ emb_w^T ----------------
__global__ __launch_bounds__(256) void k_embed(const float* __restrict__ x,
        const float* __restrict__ emb_w, float* __restrict__ h0) {
    __shared__ float w[16][16];
    int t = threadIdx.x;
    w[t >> 4][t & 15] = emb_w[t];          // 256 elems exactly
    __syncthreads();
    int idx = blockIdx.x * 256 + t;        // element index row*16+d
    int row = idx >> 4, d = idx & 15;
    const float* xr = x + (size_t)row * 16;
    float acc = 0.f;
#pragma unroll
    for (int k = 0; k < 16; ++k) acc = fmaf(xr[k], w[d][k], acc);
    h0[idx] = acc;
}

// ---------------- kernel 2: T[b,e] = adj[b,e] @ h0[b]  (384x16, K=384) ----------------
__global__ __launch_bounds__(256) void k_adj_h0(const float* __restrict__ adj,
        const float* __restrict__ h0, float* __restrict__ T1) {
    int mt = blockIdx.x, e = blockIdx.y, b = blockIdx.z;
    const float* A = adj + (size_t)(b * 3 + e) * ADJ_BE + (size_t)mt * 64 * 384;
    const float* H = h0 + (size_t)b * 384 * 16;
    __shared__ float aT[32][68];   // [k][m] transposed, pad
    __shared__ float hB[32][16];   // [k][h]
    int t = threadIdx.x;
    int txn = t & 7;               // cols: txn, txn+8
    int tym = t >> 3;              // rows: tym, tym+32  (0..31)
    float acc[2][2] = {};
    for (int k0 = 0; k0 < 384; k0 += 32) {
        __syncthreads();
#pragma unroll
        for (int p = 0; p < 2; ++p) {          // adj tile 64x32 -> transposed
            int idx = t + p * 256;             // 0..511 float4 slots
            int r = idx >> 3, q = idx & 7;
            float4 v = *(const float4*)(A + (size_t)r * 384 + k0 + q * 4);
            aT[q*4+0][r] = v.x; aT[q*4+1][r] = v.y; aT[q*4+2][r] = v.z; aT[q*4+3][r] = v.w;
        }
        if (t < 128) {                         // h0 tile 32x16
            int r = t >> 2, q = t & 3;
            float4 v = *(const float4*)(H + (size_t)(k0 + r) * 16 + q * 4);
            hB[r][q*4+0] = v.x; hB[r][q*4+1] = v.y; hB[r][q*4+2] = v.z; hB[r][q*4+3] = v.w;
        }
        __syncthreads();
#pragma unroll
        for (int k = 0; k < 32; ++k) {
            float a0 = aT[k][tym], a1 = aT[k][tym + 32];
            float b0 = hB[k][txn], b1 = hB[k][txn + 8];
            acc[0][0] = fmaf(a0, b0, acc[0][0]);
            acc[0][1] = fmaf(a0, b1, acc[0][1]);
            acc[1][0] = fmaf(a1, b0, acc[1][0]);
            acc[1][1] = fmaf(a1, b1, acc[1][1]);
        }
    }
    float* Tp = T1 + (size_t)(b * 3 + e) * (384 * 16) + (size_t)(mt * 64) * 16;
#pragma unroll
    for (int i = 0; i < 2; ++i)
#pragma unroll
        for (int j = 0; j < 2; ++j)
            Tp[(tym + 32 * i) * 16 + (txn + 8 * j)] = acc[i][j];
}

// ---------------- kernel 3: h1 = sum_e relu(T[b,e] @ W1[e])  (K=16) ----------------
__global__ __launch_bounds__(256) void k_l1s2(const float* __restrict__ T1,
        const float* __restrict__ W1, float* __restrict__ h1) {
    __shared__ float wL[3][16][128];
    __shared__ float tL[3][64][17];
    int t = threadIdx.x;
    int rt = blockIdx.x;             // 64-row tile of flattened (b*384+m)
    int b = rt / 6, m0 = (rt % 6) * 64;
#pragma unroll
    for (int p = 0; p < 6; ++p) {    // W1: 3*16*128 floats = 1536 f4
        int idx = t + p * 256;
        float4 v = *(const float4*)(W1 + (size_t)idx * 4);
        int e = idx / 512, rem = idx % 512;
        int d = rem >> 5, q = rem & 31;
        *(float4*)&wL[e][d][q * 4] = v;
    }
#pragma unroll
    for (int p = 0; p < 3; ++p) {    // T tiles: 3*64*16 = 768 f4
        int idx = t + p * 256;
        int e = idx >> 8, rem = idx & 255;
        int r = rem >> 2, q = rem & 3;
        float4 v = *(const float4*)(T1 + ((size_t)(b * 3 + e) * 384 + m0 + r) * 16 + q * 4);
        tL[e][r][q*4+0] = v.x; tL[e][r][q*4+1] = v.y; tL[e][r][q*4+2] = v.z; tL[e][r][q*4+3] = v.w;
    }
    __syncthreads();
    int tx = t & 31;                 // cols c = tx + 32j, j<4
    int ty = t >> 5;                 // rows r = ty + 8i, i<8
    float tot[8][4] = {};
#pragma unroll
    for (int e = 0; e < 3; ++e) {
        float acc[8][4] = {};
#pragma unroll
        for (int d = 0; d < 16; ++d) {
            float a[8], w[4];
#pragma unroll
            for (int i = 0; i < 8; ++i) a[i] = tL[e][ty + 8 * i][d];
#pragma unroll
            for (int j = 0; j < 4; ++j) w[j] = wL[e][d][tx + 32 * j];
#pragma unroll
            for (int i = 0; i < 8; ++i)
#pragma unroll
                for (int j = 0; j < 4; ++j)
                    acc[i][j] = fmaf(a[i], w[j], acc[i][j]);
        }
#pragma unroll
        for (int i = 0; i < 8; ++i)
#pragma unroll
            for (int j = 0; j < 4; ++j)
                tot[i][j] += fmaxf(acc[i][j], 0.f);
    }
    float* out = h1 + (size_t)rt * 64 * 128;
#pragma unroll
    for (int i = 0; i < 8; ++i)
#pragma unroll
        for (int j = 0; j < 4; ++j)
            out[(ty + 8 * i) * 128 + tx + 32 * j] = tot[i][j];
}

// ---------------- kernel 4: S[b,e] = h[b] @ W[e]  (rows x 128, K=128) ----------------
__global__ __launch_bounds__(256) void k_support(const float* __restrict__ hin,
        const float* __restrict__ W, float* __restrict__ S) {
    int rt = blockIdx.x, e = blockIdx.y;
    int b = rt / 6, n0 = (rt % 6) * 64;
    const float* Hp = hin + (size_t)rt * 64 * 128;
    const float* Wp = W + (size_t)e * 128 * 128;
    float* Sp = S + ((size_t)(b * 3 + e) * 384 + n0) * 128;
    __shared__ float aT[32][68];    // [k][row]
    __shared__ float bW[32][132];   // [k][col]
    int t = threadIdx.x;
    int tx = t & 15;                // cols c = tx + 16j, j<8
    int ty = t >> 4;                // rows r = ty + 16i, i<4
    float acc[4][8] = {};
    for (int k0 = 0; k0 < 128; k0 += 32) {
        __syncthreads();
#pragma unroll
        for (int p = 0; p < 2; ++p) {          // h tile 64x32 transposed
            int idx = t + p * 256;
            int r = idx >> 3, q = idx & 7;
            float4 v = *(const float4*)(Hp + (size_t)r * 128 + k0 + q * 4);
            aT[q*4+0][r] = v.x; aT[q*4+1][r] = v.y; aT[q*4+2][r] = v.z; aT[q*4+3][r] = v.w;
        }
#pragma unroll
        for (int p = 0; p < 4; ++p) {          // W tile 32x128
            int idx = t + p * 256;
            int r = idx >> 5, q = idx & 31;
            float4 v = *(const float4*)(Wp + (size_t)(k0 + r) * 128 + q * 4);
            *(float4*)&bW[r][q * 4] = v;
        }
        __syncthreads();
#pragma unroll
        for (int k = 0; k < 32; ++k) {
            float a[4], bb[8];
#pragma unroll
            for (int i = 0; i < 4; ++i) a[i] = aT[k][ty + 16 * i];
#pragma unroll
            for (int j = 0; j < 8; ++j) bb[j] = bW[k][tx + 16 * j];
#pragma unroll
            for (int i = 0; i < 4; ++i)
#pragma unroll
                for (int j = 0; j < 8; ++j)
                    acc[i][j] = fmaf(a[i], bb[j], acc[i][j]);
        }
    }
#pragma unroll
    for (int i = 0; i < 4; ++i)
#pragma unroll
        for (int j = 0; j < 8; ++j)
            Sp[(ty + 16 * i) * 128 + tx + 16 * j] = acc[i][j];
}

// ---------------- kernel 5: out[b] += relu?(adj[b,e] @ S[b,e])  (128x128 tile, K=384) ----------------
template <int RELU>
__global__ __launch_bounds__(256) void k_adj_gemm(const float* __restrict__ adj,
        const float* __restrict__ S, float* __restrict__ out) {
    int mt = blockIdx.x, e = blockIdx.y, b = blockIdx.z;
    const float* A = adj + (size_t)(b * 3 + e) * ADJ_BE + (size_t)mt * 128 * 384;
    const float* Bp = S + (size_t)(b * 3 + e) * 384 * 128;
    float* O = out + ((size_t)b * 384 + mt * 128) * 128;
    __shared__ float aT[32][132];   // [k][m]
    __shared__ float bT[32][132];   // [k][n]
    int t = threadIdx.x;
    int tx = t & 15;                // cols c = tx + 16j, j<8
    int ty = t >> 4;                // rows r = ty + 16i, i<8
    float acc[8][8] = {};
    for (int k0 = 0; k0 < 384; k0 += 32) {
        __syncthreads();
#pragma unroll
        for (int p = 0; p < 4; ++p) {          // adj tile 128x32 transposed
            int idx = t + p * 256;
            int r = idx >> 3, q = idx & 7;
            float4 v = *(const float4*)(A + (size_t)r * 384 + k0 + q * 4);
            aT[q*4+0][r] = v.x; aT[q*4+1][r] = v.y; aT[q*4+2][r] = v.z; aT[q*4+3][r] = v.w;
        }
#pragma unroll
        for (int p = 0; p < 4; ++p) {          // S tile 32x128
            int idx = t + p * 256;
            int r = idx >> 5, q = idx & 31;
            float4 v = *(const float4*)(Bp + (size_t)(k0 + r) * 128 + q * 4);
            *(float4*)&bT[r][q * 4] = v;
        }
        __syncthreads();
#pragma unroll
        for (int k = 0; k < 32; ++k) {
            float a[8], bb[8];
#pragma unroll
            for (int i = 0; i < 8; ++i) a[i] = aT[k][ty + 16 * i];
#pragma unroll
            for (int j = 0; j < 8; ++j) bb[j] = bT[k][tx + 16 * j];
#pragma unroll
            for (int i = 0; i < 8; ++i)
#pragma unroll
                for (int j = 0; j < 8; ++j)
                    acc[i][j] = fmaf(a[i], bb[j], acc[i][j]);
        }
    }
#pragma unroll
    for (int i = 0; i < 8; ++i) {
        int r = ty + 16 * i;
#pragma unroll
        for (int j = 0; j < 8; ++j) {
            float v = RELU ? fmaxf(acc[i][j], 0.f) : acc[i][j];
            atomicAdd(O + (size_t)r * 128 + tx + 16 * j, v);
        }
    }
}

// ---------------- zero helper ----------------
__global__ void k_zero(float* __restrict__ p, int n4) {
    int i = blockIdx.x * blockDim.x + threadIdx.x;
    if (i < n4) ((float4*)p)[i] = float4{0.f, 0.f, 0.f, 0.f};
}

// ---------------- kernel 6: fused head ----------------
__global__ __launch_bounds__(256) void k_head(const float* __restrict__ h3,
        const float* __restrict__ st_w1, const float* __restrict__ st_b1,
        const float* __restrict__ st_w2, const float* __restrict__ st_b2,
        const float* __restrict__ rescale_w, float* __restrict__ out) {
    __shared__ float hL[64][132];
    __shared__ float w1L[64][132];
    __shared__ float ytL[64][68];
    __shared__ float w2L[32][68];
    __shared__ float b1L[64], b2L[32];
    int t = threadIdx.x;
    int r0 = blockIdx.x * 64;
#pragma unroll
    for (int p = 0; p < 8; ++p) {   // h rows 64x128 = 2048 f4
        int idx = t + p * 256;
        int r = idx >> 5, q = idx & 31;
        *(float4*)&hL[r][q * 4] = *(const float4*)(h3 + (size_t)(r0 + r) * 128 + q * 4);
    }
#pragma unroll
    for (int p = 0; p < 8; ++p) {   // w1 64x128
        int idx = t + p * 256;
        int r = idx >> 5, q = idx & 31;
        *(float4*)&w1L[r][q * 4] = *(const float4*)(st_w1 + (size_t)r * 128 + q * 4);
    }
#pragma unroll
    for (int p = 0; p < 2; ++p) {   // w2 32x64 = 512 f4
        int idx = t + p * 256;
        int r = idx >> 4, q = idx & 15;
        *(float4*)&w2L[r][q * 4] = *(const float4*)(st_w2 + (size_t)r * 64 + q * 4);
    }
    if (t < 64) b1L[t] = st_b1[t];
    else if (t < 96) b2L[t - 64] = st_b2[t - 64];
    __syncthreads();
    // phase 1: y = h @ w1^T + b1, tanh
    int tx = t & 15, ty = t >> 4;
    float acc[4][4] = {};
    for (int d = 0; d < 128; ++d) {
        float a[4], w[4];
#pragma unroll
        for (int i = 0; i < 4; ++i) a[i] = hL[ty + 16 * i][d];
#pragma unroll
        for (int j = 0; j < 4; ++j) w[j] = w1L[tx + 16 * j][d];
#pragma unroll
        for (int i = 0; i < 4; ++i)
#pragma unroll
            for (int j = 0; j < 4; ++j)
                acc[i][j] = fmaf(a[i], w[j], acc[i][j]);
    }
#pragma unroll
    for (int i = 0; i < 4; ++i)
#pragma unroll
        for (int j = 0; j < 4; ++j)
            ytL[ty + 16 * i][tx + 16 * j] = tanhf(acc[i][j] + b1L[tx + 16 * j]);
    __syncthreads();
    // phase 2: z = yt @ w2^T + b2; split into s (tanh*exp(rescale)) and t
    int tx8 = t & 7, ty32 = t >> 3;
    float acc2[2][4] = {};
    for (int d = 0; d < 64; ++d) {
        float a[2], w[4];
#pragma unroll
        for (int i = 0; i < 2; ++i) a[i] = ytL[ty32 + 32 * i][d];
#pragma unroll
        for (int j = 0; j < 4; ++j) w[j] = w2L[tx8 + 8 * j][d];
#pragma unroll
        for (int i = 0; i < 2; ++i)
#pragma unroll
            for (int j = 0; j < 4; ++j)
                acc2[i][j] = fmaf(a[i], w[j], acc2[i][j]);
    }
    float er = expf(rescale_w[0]);
#pragma unroll
    for (int i = 0; i < 2; ++i) {
        int r = r0 + ty32 + 32 * i;
#pragma unroll
        for (int j = 0; j < 4; ++j) {
            int c = tx8 + 8 * j;
            float z = acc2[i][j] + b2L[c];
            if (c < 16) out[(size_t)r * 16 + c] = er * tanhf(z);
            else        out[(size_t)(ROWS + r) * 16 + (c - 16)] = z;
        }
    }
}

extern "C" void kernel_launch(void* const* d_in, const int* in_sizes, int n_in,
                              void* d_out, int out_size, void* d_ws, size_t ws_size,
                              hipStream_t stream) {
    const float* x     = (const float*)d_in[0];
    const float* adj   = (const float*)d_in[1];
    const float* emb_w = (const float*)d_in[2];
    const float* gc1   = (const float*)d_in[3];
    const float* gc2   = (const float*)d_in[4];
    const float* gc3   = (const float*)d_in[5];
    const float* st_w1 = (const float*)d_in[6];
    const float* st_b1 = (const float*)d_in[7];
    const float* st_w2 = (const float*)d_in[8];
    const float* st_b2 = (const float*)d_in[9];
    const float* resc  = (const float*)d_in[10];
    float* out = (float*)d_out;
    float* ws  = (float*)d_ws;

    // workspace layout (floats): total ~69.2 MB
    float* h0 = ws;                    // 393216
    float* T1 = h0 + 393216;           // 1179648
    float* hA = T1 + 1179648;          // 3145728 (h1, later h3)
    float* S  = hA + 3145728;          // 9437184
    float* hB = S  + 9437184;          // 3145728 (h2)

    // embed
    k_embed<<<1536, 256, 0, stream>>>(x, emb_w, h0);
    // layer 1 (reassociated): T = adj@h0, h1 = sum_e relu(T@W1)
    k_adj_h0<<<dim3(6, 3, 64), 256, 0, stream>>>(adj, h0, T1);
    k_l1s2<<<384, 256, 0, stream>>>(T1, gc1, hA);
    // layer 2
    k_support<<<dim3(384, 3), 256, 0, stream>>>(hA, gc2, S);
    k_zero<<<3072, 256, 0, stream>>>(hB, 786432);
    k_adj_gemm<1><<<dim3(3, 3, 64), 256, 0, stream>>>(adj, S, hB);
    // layer 3 (no relu)
    k_support<<<dim3(384, 3), 256, 0, stream>>>(hB, gc3, S);
    k_zero<<<3072, 256, 0, stream>>>(hA, 786432);
    k_adj_gemm<0><<<dim3(3, 3, 64), 256, 0, stream>>>(adj, S, hA);
    // head
    k_head<<<384, 256, 0, stream>>>(hA, st_w1, st_b1, st_w2, st_b2, resc, out);
}